// Round 6
// baseline (101.408 us; speedup 1.0000x reference)
//
#include <hip/hip_runtime.h>

// InteractionLayer (SchNet-style) — MFMA f16, 256-thread-block version. gfx950.
// Shapes hardcoded: B=4, N=256, NF=H=128, K=300 filters, gamma=10, spacing=0.1.
// Block = one (b,i) row: 1024 blocks x 256 threads (4 waves, wave = jg 0..3).
// Each wave computes 16 j-rows x FULL 128 h (hgrp inner loop) so:
//  - blocks are 1 wave/SIMD -> a ~5-waves/SIMD register limit gives 5 blocks/CU
//    (20 waves, 62%) instead of 2x512-thread blocks (16 waves). [round-5 lesson:
//    VGPR_Count excludes AGPR accumulators; true footprint ~96 regs/wave]
//  - rbf A-fragments computed ONCE per kk (previously duplicated across hgrp).
//  - ytile A-fragments read once per kk for both hgrp.
// GEMM1: rbf[64j x 320k] @ W1[320x128], K-steps restricted per sorted 16-row
//   group (window +-12), rbf via exact exp-recurrence in registers.
// GEMM2: ssp(y)[64x128] @ W2[128x128] dense.
// W1/W2 B-fragments read directly from global (pre-packed, L1/L2-resident).
// ssp via direct form: ln2*log2(0.5*exp2(x*log2e)+0.5); GEMM2 keeps log2-domain
// in sumv and scales by ln2 once in the reduction.
//
// MFMA 16x16x32 layouts (gfx950):
//   A: lane l elem j -> A[l&15][(l>>4)*8 + j]
//   B: lane l elem j -> B[(l>>4)*8 + j][l&15]
//   D: lane l reg  r -> D[(l>>4)*4 + r][l&15]

typedef _Float16 f16x8 __attribute__((ext_vector_type(8)));
typedef float f32x4 __attribute__((ext_vector_type(4)));

__device__ __forceinline__ float exp2f_fast(float x) {
#if __has_builtin(__builtin_amdgcn_exp2f)
  return __builtin_amdgcn_exp2f(x);
#else
  return __exp2f(x);
#endif
}
__device__ __forceinline__ float log2f_fast(float x) {
#if __has_builtin(__builtin_amdgcn_logf)
  return __builtin_amdgcn_logf(x);
#else
  return __log2f(x);
#endif
}

// log2-domain ssp: log2(0.5*e^x + 0.5).  ssp(x) = ln2 * ssp_l2(x).
__device__ __forceinline__ float ssp_l2(float x) {
  return log2f_fast(fmaf(0.5f, exp2f_fast(1.44269504f * x), 0.5f));
}

// Pack W1 [300,128] -> f16 B-frag layout [10kk][8nt][64l][8j] at ws[0..40960)
// and W2 [128,128] -> [4kk][8nt][64l][8j] at ws[40960..57344).
__global__ void prep_pack(const float* __restrict__ W1, const float* __restrict__ W2,
                          unsigned short* __restrict__ ws) {
  int gid = blockIdx.x * 256 + threadIdx.x;
  if (gid < 40960) {
    int j = gid & 7, l = (gid >> 3) & 63, ntg = (gid >> 9) & 7, kk = gid >> 12;
    int k = kk * 32 + (l >> 4) * 8 + j;
    int h = ntg * 16 + (l & 15);
    float v = (k < 300) ? W1[k * 128 + h] : 0.f;
    ws[gid] = __builtin_bit_cast(unsigned short, (_Float16)v);
  } else if (gid < 57344) {
    int g2 = gid - 40960;
    int j = g2 & 7, l = (g2 >> 3) & 63, ntg = (g2 >> 9) & 7, kk = g2 >> 12;
    int k = kk * 32 + (l >> 4) * 8 + j;
    int h = ntg * 16 + (l & 15);
    ws[gid] = __builtin_bit_cast(unsigned short, (_Float16)W2[k * 128 + h]);
  }
}

__global__ __launch_bounds__(256, 4) void interaction_kernel(
    const float* __restrict__ nodef, const float* __restrict__ pos,
    const float* __restrict__ valid, const unsigned short* __restrict__ ws,
    const float* __restrict__ Wa1, const float* __restrict__ Wa2,
    const float* __restrict__ Wa3, float* __restrict__ out) {
  __shared__ __align__(16) _Float16 ytile[64 * 136];  // 17,408 B (reused as f32 red)
  __shared__ float d_lds[256];
  __shared__ int k0arr[256];
  __shared__ unsigned short jord[256];
  __shared__ int kklo[16], kkhi[16];
  __shared__ float xrow[128], h1row[128], hhrow[128], a2row[128];
  __shared__ float partial[2][128];

  const int t = threadIdx.x;
  const int bid = blockIdx.x;  // b*256 + i
  const int b = bid >> 8;
  const unsigned short* __restrict__ W2g = ws + 40960;

  if (t < 128) xrow[t] = nodef[bid * 128 + t];
  {
    const float qx = pos[bid * 3 + 0], qy = pos[bid * 3 + 1], qz = pos[bid * 3 + 2];
    const float px = pos[(b * 256 + t) * 3 + 0];
    const float py = pos[(b * 256 + t) * 3 + 1];
    const float pz = pos[(b * 256 + t) * 3 + 2];
    const float dx = px - qx, dy = py - qy, dz = pz - qz;
    const float dd = sqrtf(dx * dx + dy * dy + dz * dz);
    d_lds[t] = dd;
    k0arr[t] = __float2int_rn(dd * 10.f);
  }
  __syncthreads();

  // ---- stable rank-sort of j by window center (deterministic) ----
  {
    const int key = k0arr[t];
    int rank = 0;
    for (int j2 = 0; j2 < 256; ++j2) {
      const int k2 = k0arr[j2];
      rank += (k2 < key || (k2 == key && j2 < t)) ? 1 : 0;
    }
    jord[rank] = (unsigned short)t;
  }
  // h1 = x @ Wa1 (2 partial groups of 64 k each)
  {
    const int hh_ = t & 127, part = t >> 7;
    float a = 0.f;
#pragma unroll 8
    for (int k = part * 64; k < part * 64 + 64; ++k) a += xrow[k] * Wa1[k * 128 + hh_];
    partial[part][hh_] = a;
  }
  __syncthreads();
  // per sorted-16-group K-step ranges (window +-12: exp(-10*1.2^2)=5.6e-7)
  if (t < 16) {
    const int base = t * 16;
    const int klo = max(0, k0arr[jord[base]] - 12);
    const int khi = min(319, k0arr[jord[base + 15]] + 12);
    kklo[t] = klo >> 5;
    kkhi[t] = (khi >> 5) + 1;
  }
  if (t < 128) h1row[t] = partial[0][t] + partial[1][t];
  __syncthreads();

  const int jg = t >> 6, l = t & 63;  // wave jg: rows jg*16..+16, full 128 h
  const int lr = l & 15, lq = l >> 4;
  float sumv[8];
#pragma unroll
  for (int r = 0; r < 8; ++r) sumv[r] = 0.f;

  // ---- main loop: 4 chunks of 64 sorted j's ----
  for (int cc = 0; cc < 4; ++cc) {
    const int g = cc * 4 + jg;
    const float dd = d_lds[jord[cc * 64 + jg * 16 + lr]];
    const int lo = kklo[g], hi = kkhi[g];

    // GEMM1: acc[hg*4+nt] (16j x 16h tiles), K-steps restricted to group window.
    f32x4 acc[8];
#pragma unroll
    for (int r = 0; r < 8; ++r) acc[r] = f32x4{0, 0, 0, 0};
    for (int kk = lo; kk < hi; ++kk) {
      // rbf via exact exp recurrence (computed ONCE, feeds 8 MFMAs):
      // a_j = -10*(x0-0.1j)^2; a_{j+1}-a_j = 2x0-0.2j-0.1 -> v *= r, r *= e^-0.2.
      const float x0 = dd - 0.1f * (float)(kk * 32 + lq * 8);
      float v = exp2f_fast(-14.4269504f * x0 * x0);                // e^{a_0}
      float r = exp2f_fast(fmaf(2.88539008f, x0, -0.144269504f));  // e^{2x0-0.1}
      f16x8 afr;
      afr[0] = (_Float16)v;
#pragma unroll
      for (int j = 1; j < 8; ++j) {
        v *= r;
        r *= 0.818730753f;  // e^-0.2
        afr[j] = (_Float16)v;
      }
#pragma unroll
      for (int hg = 0; hg < 2; ++hg)
#pragma unroll
        for (int nt = 0; nt < 4; ++nt) {
          const f16x8 bfr =
              *(const f16x8*)&ws[((kk * 8 + hg * 4 + nt) * 64 + l) * 8];
          acc[hg * 4 + nt] =
              __builtin_amdgcn_mfma_f32_16x16x32_f16(afr, bfr, acc[hg * 4 + nt], 0, 0, 0);
        }
    }
    // ssp -> y tile (f16)
#pragma unroll
    for (int hg = 0; hg < 2; ++hg)
#pragma unroll
      for (int nt = 0; nt < 4; ++nt)
#pragma unroll
        for (int r = 0; r < 4; ++r)
          ytile[(jg * 16 + lq * 4 + r) * 136 + hg * 64 + nt * 16 + lr] =
              (_Float16)(0.69314718f * ssp_l2(acc[hg * 4 + nt][r]));
    __syncthreads();

    // GEMM2: z = y @ W2 (dense K=128); A-frag read once serves both hg.
    f32x4 acc2[8];
#pragma unroll
    for (int r = 0; r < 8; ++r) acc2[r] = f32x4{0, 0, 0, 0};
#pragma unroll
    for (int kk = 0; kk < 4; ++kk) {
      const f16x8 afr = *(const f16x8*)&ytile[(jg * 16 + lr) * 136 + kk * 32 + lq * 8];
#pragma unroll
      for (int hg = 0; hg < 2; ++hg)
#pragma unroll
        for (int nt = 0; nt < 4; ++nt) {
          const f16x8 bfr =
              *(const f16x8*)&W2g[((kk * 8 + hg * 4 + nt) * 64 + l) * 8];
          acc2[hg * 4 + nt] =
              __builtin_amdgcn_mfma_f32_16x16x32_f16(afr, bfr, acc2[hg * 4 + nt], 0, 0, 0);
        }
    }
    // accumulate sum_j in log2 domain (scale by ln2 once at the end)
#pragma unroll
    for (int q = 0; q < 8; ++q)
#pragma unroll
      for (int r = 0; r < 4; ++r) sumv[q] += ssp_l2(acc2[q][r]);
    __syncthreads();  // ytile safe to overwrite next chunk
  }

  // ---- reduce sum_j partials (16 per h-column) via f32 scratch over ytile ----
  {
    float* red = (float*)ytile;
#pragma unroll
    for (int hg = 0; hg < 2; ++hg)
#pragma unroll
      for (int nt = 0; nt < 4; ++nt)
        red[(jg * 4 + lq) * 128 + hg * 64 + nt * 16 + lr] =
            0.69314718f * sumv[hg * 4 + nt];
  }
  __syncthreads();
  if (t < 128) {
    const float* red = (const float*)ytile;
    float s = 0.f;
#pragma unroll
    for (int q = 0; q < 16; ++q) s += red[q * 128 + t];
    hhrow[t] = h1row[t] * s;  // CFConv: h * sum_j filt
  }
  __syncthreads();
  // a2 = ssp(hh @ Wa2)
  {
    const int hh_ = t & 127, part = t >> 7;
    float a = 0.f;
#pragma unroll 8
    for (int k = part * 64; k < part * 64 + 64; ++k) a += hhrow[k] * Wa2[k * 128 + hh_];
    partial[part][hh_] = a;
  }
  __syncthreads();
  if (t < 128)
    a2row[t] = 0.69314718f * ssp_l2(partial[0][t] + partial[1][t]);
  __syncthreads();
  // out = x + (a2 @ Wa3) * valid
  {
    const int hh_ = t & 127, part = t >> 7;
    float a = 0.f;
#pragma unroll 8
    for (int k = part * 64; k < part * 64 + 64; ++k) a += a2row[k] * Wa3[k * 128 + hh_];
    partial[part][hh_] = a;
  }
  __syncthreads();
  if (t < 128)
    out[bid * 128 + t] = xrow[t] + (partial[0][t] + partial[1][t]) * valid[bid];
}

extern "C" void kernel_launch(void* const* d_in, const int* in_sizes, int n_in,
                              void* d_out, int out_size, void* d_ws, size_t ws_size,
                              hipStream_t stream) {
  const float* nodef = (const float*)d_in[0];
  const float* pos   = (const float*)d_in[1];
  const float* valid = (const float*)d_in[2];
  const float* W1    = (const float*)d_in[3];
  const float* W2    = (const float*)d_in[4];
  const float* Wa1   = (const float*)d_in[5];
  const float* Wa2   = (const float*)d_in[6];
  const float* Wa3   = (const float*)d_in[7];
  float* outp = (float*)d_out;
  unsigned short* wsp = (unsigned short*)d_ws;  // 57,344 f16 = 114,688 B

  prep_pack<<<224, 256, 0, stream>>>(W1, W2, wsp);
  interaction_kernel<<<1024, 256, 0, stream>>>(nodef, pos, valid, wsp,
                                               Wa1, Wa2, Wa3, outp);
}

// Round 8
// 62.642 us; speedup vs baseline: 1.6188x; 1.6188x over previous
//
#include <hip/hip_runtime.h>

// InteractionLayer (SchNet-style) — MFMA f16, round-5 base + reg-merge. gfx950.
// Shapes hardcoded: B=4, N=256, NF=H=128, K=300 filters, gamma=10, spacing=0.1.
// Block = one (b,i) row: 1024 blocks x 512 threads (8 waves: jg 0..3 x hgrp 0..1).
// ~22 KB LDS; ONE merged f32x4 acc[4] for both GEMMs (never simultaneously live)
// -> unified VGPR+acc footprint ~80/wave; tests whether HW allocates waves at
// 512/V granularity (-> 3 blocks/CU, 24 waves) vs power-of-2 steps (-> 16 waves).
// [round-7 lesson: one unproven change per round — ballot sort reverted to the
//  proven rank sort; round-4/6 lesson: never force launch_bounds below usage.]
// GEMM1: rbf[64j x 320k] @ W1[320x128]; rbf via exact exp-recurrence in regs;
//   K-steps restricted per sorted 16-row group (window +-12).
// GEMM2: ssp(y)[64x128] @ W2[128x128] dense.
// W1/W2 B-fragments read directly from global (pre-packed, L1/L2-resident).
// ssp in log2 domain (proven round 6): ssp(x) = ln2*log2(0.5*exp2(x*log2e)+0.5);
// sum_j kept in log2 domain, scaled by ln2 once in the reduction.
//
// MFMA 16x16x32 layouts (gfx950):
//   A: lane l elem j -> A[l&15][(l>>4)*8 + j]
//   B: lane l elem j -> B[(l>>4)*8 + j][l&15]
//   D: lane l reg  r -> D[(l>>4)*4 + r][l&15]

typedef _Float16 f16x8 __attribute__((ext_vector_type(8)));
typedef float f32x4 __attribute__((ext_vector_type(4)));

__device__ __forceinline__ float exp2f_fast(float x) {
#if __has_builtin(__builtin_amdgcn_exp2f)
  return __builtin_amdgcn_exp2f(x);
#else
  return __exp2f(x);
#endif
}
__device__ __forceinline__ float log2f_fast(float x) {
#if __has_builtin(__builtin_amdgcn_logf)
  return __builtin_amdgcn_logf(x);
#else
  return __log2f(x);
#endif
}

// log2-domain ssp: log2(0.5*e^x + 0.5).  ssp(x) = ln2 * ssp_l2(x).
__device__ __forceinline__ float ssp_l2(float x) {
  return log2f_fast(fmaf(0.5f, exp2f_fast(1.44269504f * x), 0.5f));
}

// Pack W1 [300,128] -> f16 B-frag layout [10kk][8nt][64l][8j] at ws[0..40960)
// and W2 [128,128] -> [4kk][8nt][64l][8j] at ws[40960..57344).
__global__ void prep_pack(const float* __restrict__ W1, const float* __restrict__ W2,
                          unsigned short* __restrict__ ws) {
  int gid = blockIdx.x * 256 + threadIdx.x;
  if (gid < 40960) {
    int j = gid & 7, l = (gid >> 3) & 63, ntg = (gid >> 9) & 7, kk = gid >> 12;
    int k = kk * 32 + (l >> 4) * 8 + j;
    int h = ntg * 16 + (l & 15);
    float v = (k < 300) ? W1[k * 128 + h] : 0.f;
    ws[gid] = __builtin_bit_cast(unsigned short, (_Float16)v);
  } else if (gid < 57344) {
    int g2 = gid - 40960;
    int j = g2 & 7, l = (g2 >> 3) & 63, ntg = (g2 >> 9) & 7, kk = g2 >> 12;
    int k = kk * 32 + (l >> 4) * 8 + j;
    int h = ntg * 16 + (l & 15);
    ws[gid] = __builtin_bit_cast(unsigned short, (_Float16)W2[k * 128 + h]);
  }
}

__global__ __launch_bounds__(512, 4) void interaction_kernel(
    const float* __restrict__ nodef, const float* __restrict__ pos,
    const float* __restrict__ valid, const unsigned short* __restrict__ ws,
    const float* __restrict__ Wa1, const float* __restrict__ Wa2,
    const float* __restrict__ Wa3, float* __restrict__ out) {
  __shared__ __align__(16) _Float16 ytile[64 * 136];  // 17,408 B (reused as f32 red)
  __shared__ float d_lds[256];
  __shared__ int k0arr[256];
  __shared__ unsigned short jord[256];
  __shared__ int kklo[16], kkhi[16];
  __shared__ float xrow[128], h1row[128], hhrow[128], a2row[128];
  __shared__ float partial[4][128];

  const int t = threadIdx.x;
  const int bid = blockIdx.x;  // b*256 + i
  const int b = bid >> 8;
  const unsigned short* __restrict__ W2g = ws + 40960;

  if (t < 128) xrow[t] = nodef[bid * 128 + t];
  if (t < 256) {
    const float qx = pos[bid * 3 + 0], qy = pos[bid * 3 + 1], qz = pos[bid * 3 + 2];
    const float px = pos[(b * 256 + t) * 3 + 0];
    const float py = pos[(b * 256 + t) * 3 + 1];
    const float pz = pos[(b * 256 + t) * 3 + 2];
    const float dx = px - qx, dy = py - qy, dz = pz - qz;
    const float dd = sqrtf(dx * dx + dy * dy + dz * dz);
    d_lds[t] = dd;
    k0arr[t] = __float2int_rn(dd * 10.f);
  }
  __syncthreads();

  // ---- stable rank-sort of j by window center (deterministic, proven) ----
  if (t < 256) {
    const int key = k0arr[t];
    int rank = 0;
    for (int j2 = 0; j2 < 256; ++j2) {
      const int k2 = k0arr[j2];
      rank += (k2 < key || (k2 == key && j2 < t)) ? 1 : 0;
    }
    jord[rank] = (unsigned short)t;
  }
  // h1 = x @ Wa1 (partials over 4 thread-groups)
  {
    const int hh_ = t & 127, part = t >> 7;
    float a = 0.f;
#pragma unroll 8
    for (int k = part * 32; k < part * 32 + 32; ++k) a += xrow[k] * Wa1[k * 128 + hh_];
    partial[part][hh_] = a;
  }
  __syncthreads();
  // per sorted-16-group K-step ranges (window +-12: exp(-10*1.2^2)=5.6e-7)
  if (t < 16) {
    const int base = t * 16;
    const int klo = max(0, k0arr[jord[base]] - 12);
    const int khi = min(319, k0arr[jord[base + 15]] + 12);
    kklo[t] = klo >> 5;
    kkhi[t] = (khi >> 5) + 1;
  }
  if (t < 128)
    h1row[t] = partial[0][t] + partial[1][t] + partial[2][t] + partial[3][t];
  __syncthreads();

  const int wid = t >> 6, l = t & 63;
  const int jg = wid >> 1, hgrp = wid & 1;  // wave tile: 16 j-rows x 64 h-cols
  const int lr = l & 15, lq = l >> 4;
  float sumv[4] = {0.f, 0.f, 0.f, 0.f};
  f32x4 acc[4];  // ONE accumulator set, reused by GEMM1 and GEMM2 (reg-lean)

  // ---- main loop: 4 chunks of 64 sorted j's ----
  for (int cc = 0; cc < 4; ++cc) {
    const int g = cc * 4 + jg;
    const float dd = d_lds[jord[cc * 64 + jg * 16 + lr]];
    const int lo = kklo[g], hi = kkhi[g];

    // GEMM1: 16j x 64h, K-steps restricted to group window.
#pragma unroll
    for (int r = 0; r < 4; ++r) acc[r] = f32x4{0, 0, 0, 0};
    for (int kk = lo; kk < hi; ++kk) {
      // rbf via exact exp recurrence: a_j = -10*(x0-0.1j)^2;
      // a_{j+1}-a_j = 2x0-0.2j-0.1 -> v *= r, r *= e^-0.2. Underflow -> exact 0.
      const float x0 = dd - 0.1f * (float)(kk * 32 + lq * 8);
      float v = exp2f_fast(-14.4269504f * x0 * x0);                // e^{a_0}
      float r = exp2f_fast(fmaf(2.88539008f, x0, -0.144269504f));  // e^{2x0-0.1}
      f16x8 afr;
      afr[0] = (_Float16)v;
#pragma unroll
      for (int j = 1; j < 8; ++j) {
        v *= r;
        r *= 0.818730753f;  // e^-0.2
        afr[j] = (_Float16)v;
      }
#pragma unroll
      for (int nt = 0; nt < 4; ++nt) {
        const f16x8 bfr = *(const f16x8*)&ws[((kk * 8 + hgrp * 4 + nt) * 64 + l) * 8];
        acc[nt] = __builtin_amdgcn_mfma_f32_16x16x32_f16(afr, bfr, acc[nt], 0, 0, 0);
      }
    }
    // ssp -> y tile (f16)
#pragma unroll
    for (int nt = 0; nt < 4; ++nt)
#pragma unroll
      for (int r = 0; r < 4; ++r)
        ytile[(jg * 16 + lq * 4 + r) * 136 + hgrp * 64 + nt * 16 + lr] =
            (_Float16)(0.69314718f * ssp_l2(acc[nt][r]));
    __syncthreads();

    // GEMM2: z = y @ W2 (dense K=128), same acc registers.
#pragma unroll
    for (int r = 0; r < 4; ++r) acc[r] = f32x4{0, 0, 0, 0};
#pragma unroll
    for (int kk = 0; kk < 4; ++kk) {
      const f16x8 afr = *(const f16x8*)&ytile[(jg * 16 + lr) * 136 + kk * 32 + lq * 8];
#pragma unroll
      for (int nt = 0; nt < 4; ++nt) {
        const f16x8 bfr = *(const f16x8*)&W2g[((kk * 8 + hgrp * 4 + nt) * 64 + l) * 8];
        acc[nt] = __builtin_amdgcn_mfma_f32_16x16x32_f16(afr, bfr, acc[nt], 0, 0, 0);
      }
    }
    // accumulate sum_j in log2 domain (ln2 applied once in the reduction)
#pragma unroll
    for (int nt = 0; nt < 4; ++nt)
#pragma unroll
      for (int r = 0; r < 4; ++r) sumv[nt] += ssp_l2(acc[nt][r]);
    __syncthreads();  // ytile safe to overwrite next chunk
  }

  // ---- reduce sum_j partials (16 per h-column) via f32 scratch over ytile ----
  {
    float* red = (float*)ytile;
#pragma unroll
    for (int nt = 0; nt < 4; ++nt)
      red[(jg * 4 + lq) * 128 + hgrp * 64 + nt * 16 + lr] = 0.69314718f * sumv[nt];
  }
  __syncthreads();
  if (t < 128) {
    const float* red = (const float*)ytile;
    float s = 0.f;
#pragma unroll
    for (int q = 0; q < 16; ++q) s += red[q * 128 + t];
    hhrow[t] = h1row[t] * s;  // CFConv: h * sum_j filt
  }
  __syncthreads();
  // a2 = ssp(hh @ Wa2)
  {
    const int hh_ = t & 127, part = t >> 7;
    float a = 0.f;
#pragma unroll 8
    for (int k = part * 32; k < part * 32 + 32; ++k) a += hhrow[k] * Wa2[k * 128 + hh_];
    partial[part][hh_] = a;
  }
  __syncthreads();
  if (t < 128)
    a2row[t] = 0.69314718f *
               ssp_l2(partial[0][t] + partial[1][t] + partial[2][t] + partial[3][t]);
  __syncthreads();
  // out = x + (a2 @ Wa3) * valid
  {
    const int hh_ = t & 127, part = t >> 7;
    float a = 0.f;
#pragma unroll 8
    for (int k = part * 32; k < part * 32 + 32; ++k) a += a2row[k] * Wa3[k * 128 + hh_];
    partial[part][hh_] = a;
  }
  __syncthreads();
  if (t < 128)
    out[bid * 128 + t] =
        xrow[t] + (partial[0][t] + partial[1][t] + partial[2][t] + partial[3][t]) * valid[bid];
}

extern "C" void kernel_launch(void* const* d_in, const int* in_sizes, int n_in,
                              void* d_out, int out_size, void* d_ws, size_t ws_size,
                              hipStream_t stream) {
  const float* nodef = (const float*)d_in[0];
  const float* pos   = (const float*)d_in[1];
  const float* valid = (const float*)d_in[2];
  const float* W1    = (const float*)d_in[3];
  const float* W2    = (const float*)d_in[4];
  const float* Wa1   = (const float*)d_in[5];
  const float* Wa2   = (const float*)d_in[6];
  const float* Wa3   = (const float*)d_in[7];
  float* outp = (float*)d_out;
  unsigned short* wsp = (unsigned short*)d_ws;  // 57,344 f16 = 114,688 B

  prep_pack<<<224, 256, 0, stream>>>(W1, W2, wsp);
  interaction_kernel<<<1024, 512, 0, stream>>>(nodef, pos, valid, wsp,
                                               Wa1, Wa2, Wa3, outp);
}